// Round 3
// baseline (2431.135 us; speedup 1.0000x reference)
//
#include <hip/hip_runtime.h>
#include <math.h>
#include <type_traits>

// ---------------------------------------------------------------------------
// BivariateNormalAttention pipeline.
// Round 2: conv1/conv2 MFMA implicit GEMM, restructured:
//   - K = tap-major (kc = 1 tap x 32 ci), no tap padding (144/72 K-chunks).
//   - B-frags read DIRECTLY from global (L2-resident wprep, 1KB contiguous
//     per wave-read), register-prefetched 1 K-step ahead. No W LDS, no W
//     staging barriers.
//   - A in LDS: [2 planes][324 halo pix][64B = 32 ci bf16], XOR slot swizzle
//     (slot ^= (pix>>1)&3) -> 2-way banks (free). A preloaded to regs one
//     chunk ahead (issue-early), split hi/lo at ds_write time.
//   - 2 barriers per 32-ci chunk; 9 MFMA K-steps between barriers.
//   MFMA 16x16x32_bf16, 3-product hi/lo split (AhBh + AhBl + AlBh).
// ---------------------------------------------------------------------------

typedef __attribute__((ext_vector_type(8))) short short8v;
typedef __attribute__((ext_vector_type(4))) float f32x4;

__device__ __forceinline__ void split_bf16(float f, unsigned int& hi, unsigned int& lo)
{
    unsigned int u = __float_as_uint(f);
    hi = u >> 16;                                    // truncated bf16 hi
    float hif = __uint_as_float(u & 0xffff0000u);
    lo = __float_as_uint(f - hif) >> 16;             // residual, truncated
}

// wprep layout: [cotile 4][ch CIN/32][tap 9][plane 2][co 64][k 32] u16.
// Per (cotile,ch,tap,plane): 4KB block; B-frag nf = contiguous 1KB at nf*1024.
__global__ __launch_bounds__(256)
void prep_w_kernel(const float* __restrict__ w, unsigned short* __restrict__ wp, int CIN)
{
    int idx = blockIdx.x * 256 + threadIdx.x;
    int NCHUNK = CIN >> 5;
    int total = 4 * NCHUNK * 9 * 2 * 2048;
    if (idx >= total) return;
    int k = idx & 31;
    int co = (idx >> 5) & 63;
    int plane = (idx >> 11) & 1;
    int blk = idx >> 12;             // (cotile, ch, tap)
    int tap = blk % 9;
    int rest = blk / 9;
    int ch = rest % NCHUNK;
    int cotile = rest / NCHUNK;
    int ci = ch * 32 + k;
    int cog = cotile * 64 + co;
    float f = w[((size_t)cog * CIN + ci) * 9 + tap];
    unsigned int hi, lo;
    split_bf16(f, hi, lo);
    wp[idx] = (unsigned short)(plane ? lo : hi);
}

// POOL=false: conv1 (fp32 input x), writes packed bf16-pair h1p (u32).
// POOL=true : conv2 (packed input h1p), writes pooled fp32 [B,256,7,7].
template<int CIN, bool POOL>
__global__ __launch_bounds__(256)
void conv_mfma_kernel(const void* __restrict__ in_, const unsigned short* __restrict__ wp,
                      const float* __restrict__ gam, const float* __restrict__ bet,
                      void* __restrict__ out_)
{
    constexpr int NCHUNK = CIN >> 5;
    using LT = typename std::conditional<POOL, unsigned int, float>::type;

    __shared__ __align__(16) char sA[41472];   // [2 planes][324 pix][64B]

    const int tid = threadIdx.x;
    const int lane = tid & 63;
    const int wv = tid >> 6;         // 4 waves
    const int m = lane & 15;         // A row (x within tile)
    const int kg = lane >> 4;        // k-octet
    const int ty = blockIdx.x / 7, tx = blockIdx.x % 7;
    const int co0 = blockIdx.y * 64;
    const int b = blockIdx.z;

    // ---- staging pixel geometry (halo 18x18 = 324 pixels)
    const int py0 = tid / 18, px0 = tid % 18;                 // pixel tid (<256)
    const long long gy0 = ty * 16 + py0 - 1, gx0 = tx * 16 + px0 - 1;
    const bool ok0 = ((unsigned long long)gy0 < 112ull) && ((unsigned long long)gx0 < 112ull);
    const int p1 = tid + 256;                                 // pixel 256..323 (tid<68)
    const int py1 = p1 / 18, px1 = p1 % 18;
    const long long gy1 = ty * 16 + py1 - 1, gx1 = tx * 16 + px1 - 1;
    const bool ok1 = (tid < 68) && ((unsigned long long)gy1 < 112ull) && ((unsigned long long)gx1 < 112ull);

    // ---- B global base: per (ch,tap): 8KB (2 planes x 4KB); lane offset in plane
    const char* wb = (const char*)wp + (size_t)blockIdx.y * ((size_t)NCHUNK * 9 * 2 * 4096);
    const int boff = (lane & 15) * 64 + kg * 16;

    LT pre[32];
    auto preload = [&](int ch) {
        const LT* src = (const LT*)in_ + ((size_t)(b * CIN + ch * 32)) * 12544
                        + gy0 * 112 + gx0;
        #pragma unroll
        for (int c = 0; c < 32; ++c)
            pre[c] = ok0 ? src[(size_t)c * 12544] : (LT)0;
    };

    auto stage_write = [&](int pix, const LT* v) {
        unsigned int hw[16], lw[16];
        #pragma unroll
        for (int i = 0; i < 16; ++i) {
            if constexpr (!POOL) {
                unsigned int h0, l0, h1, l1;
                split_bf16((float)v[2 * i], h0, l0);
                split_bf16((float)v[2 * i + 1], h1, l1);
                hw[i] = h0 | (h1 << 16);
                lw[i] = l0 | (l1 << 16);
            } else {
                unsigned int u0 = (unsigned int)v[2 * i], u1 = (unsigned int)v[2 * i + 1];
                hw[i] = (u0 & 0xffffu) | (u1 << 16);
                lw[i] = (u0 >> 16) | (u1 & 0xffff0000u);
            }
        }
        const int sl = (pix >> 1) & 3;
        char* ph = sA + pix * 64;
        #pragma unroll
        for (int c = 0; c < 4; ++c) {
            *(uint4*)(ph + ((c ^ sl) << 4)) =
                make_uint4(hw[4 * c], hw[4 * c + 1], hw[4 * c + 2], hw[4 * c + 3]);
            *(uint4*)(ph + 20736 + ((c ^ sl) << 4)) =
                make_uint4(lw[4 * c], lw[4 * c + 1], lw[4 * c + 2], lw[4 * c + 3]);
        }
    };

    f32x4 acc[4][4];
    #pragma unroll
    for (int i = 0; i < 4; ++i)
        #pragma unroll
        for (int j = 0; j < 4; ++j)
            acc[i][j] = (f32x4){0.f, 0.f, 0.f, 0.f};

    preload(0);
    short8v Bh[4], Bl[4];
    {
        const char* gb = wb + boff;
        #pragma unroll
        for (int nf = 0; nf < 4; ++nf) {
            Bh[nf] = *(const short8v*)(gb + nf * 1024);
            Bl[nf] = *(const short8v*)(gb + 4096 + nf * 1024);
        }
    }

    for (int ch = 0; ch < NCHUNK; ++ch) {
        __syncthreads();                  // previous chunk's reads done
        stage_write(tid, pre);            // pre dies here
        if (tid < 68) {
            LT tmp[32];
            const LT* src = (const LT*)in_ + ((size_t)(b * CIN + ch * 32)) * 12544
                            + gy1 * 112 + gx1;
            #pragma unroll
            for (int c = 0; c < 32; ++c)
                tmp[c] = ok1 ? src[(size_t)c * 12544] : (LT)0;
            stage_write(p1, tmp);
        }
        __syncthreads();
        if (ch + 1 < NCHUNK) preload(ch + 1);   // issue early; hides under 9 taps

        #pragma unroll
        for (int tap = 0; tap < 9; ++tap) {
            // prefetch next K-step's B frags
            short8v Bh2[4], Bl2[4];
            {
                const int ntap = (tap == 8) ? 0 : tap + 1;
                const int nch = (tap == 8) ? ((ch + 1 < NCHUNK) ? ch + 1 : ch) : ch;
                const char* gb = wb + ((size_t)(nch * 9 + ntap) * 2) * 4096 + boff;
                #pragma unroll
                for (int nf = 0; nf < 4; ++nf) {
                    Bh2[nf] = *(const short8v*)(gb + nf * 1024);
                    Bl2[nf] = *(const short8v*)(gb + 4096 + nf * 1024);
                }
            }
            const int ky = tap / 3, kx = tap % 3;
            short8v Ah[4], Al[4];
            #pragma unroll
            for (int mf = 0; mf < 4; ++mf) {
                int ap = (wv * 4 + mf + ky) * 18 + kx + m;
                int off = ap * 64 + ((kg ^ ((ap >> 1) & 3)) << 4);
                Ah[mf] = *(const short8v*)(sA + off);
                Al[mf] = *(const short8v*)(sA + 20736 + off);
            }
            #pragma unroll
            for (int mf = 0; mf < 4; ++mf)
                #pragma unroll
                for (int nf = 0; nf < 4; ++nf) {
                    acc[mf][nf] = __builtin_amdgcn_mfma_f32_16x16x32_bf16(Ah[mf], Bh[nf], acc[mf][nf], 0, 0, 0);
                    acc[mf][nf] = __builtin_amdgcn_mfma_f32_16x16x32_bf16(Ah[mf], Bl[nf], acc[mf][nf], 0, 0, 0);
                    acc[mf][nf] = __builtin_amdgcn_mfma_f32_16x16x32_bf16(Al[mf], Bh[nf], acc[mf][nf], 0, 0, 0);
                }
            #pragma unroll
            for (int nf = 0; nf < 4; ++nf) { Bh[nf] = Bh2[nf]; Bl[nf] = Bl2[nf]; }
        }
    }

    const float kRS = 1.0f / sqrtf(1.0f + 1e-5f);

    if (!POOL) {
        unsigned int* h1p = (unsigned int*)out_;
        #pragma unroll
        for (int nf = 0; nf < 4; ++nf) {
            int co = co0 + nf * 16 + (lane & 15);
            float sc = gam[co] * kRS, bi = bet[co];
            #pragma unroll
            for (int mf = 0; mf < 4; ++mf) {
                int gy = ty * 16 + wv * 4 + mf;
                int gx = tx * 16 + kg * 4;
                unsigned int pk[4];
                #pragma unroll
                for (int r = 0; r < 4; ++r) {
                    float v = fmaxf(fmaf(acc[mf][nf][r], sc, bi), 0.f);
                    unsigned int h, l;
                    split_bf16(v, h, l);
                    pk[r] = h | (l << 16);
                }
                *(uint4*)&h1p[(((size_t)b * 256 + co) * 112 + gy) * 112 + gx] =
                    make_uint4(pk[0], pk[1], pk[2], pk[3]);
            }
        }
    } else {
        __syncthreads();                      // all waves done reading sA
        float* spool = (float*)sA;            // 4 waves x 4 nf x 16 co floats
        #pragma unroll
        for (int nf = 0; nf < 4; ++nf) {
            int co = co0 + nf * 16 + (lane & 15);
            float sc = gam[co] * kRS, bi = bet[co];
            float s = 0.f;
            #pragma unroll
            for (int mf = 0; mf < 4; ++mf)
                #pragma unroll
                for (int r = 0; r < 4; ++r)
                    s += fmaxf(fmaf(acc[mf][nf][r], sc, bi), 0.f);
            s += __shfl_xor(s, 16);
            s += __shfl_xor(s, 32);
            if (lane < 16) spool[(wv * 4 + nf) * 16 + lane] = s;
        }
        __syncthreads();
        if (tid < 64) {
            float s = 0.f;
            #pragma unroll
            for (int w2 = 0; w2 < 4; ++w2)
                s += spool[(w2 * 4 + (tid >> 4)) * 16 + (tid & 15)];
            float* p1o = (float*)out_;
            p1o[(((size_t)b * 256 + co0 + tid) * 7 + ty) * 7 + tx] = s * (1.f / 256.f);
        }
    }
}

// ---------------- small downstream stages (unchanged) ----------------------

template<int CIN>
__global__ __launch_bounds__(256)
void conv_small_kernel(const float* __restrict__ in, const float* __restrict__ w,
                       const float* __restrict__ gam, const float* __restrict__ bet,
                       float* __restrict__ out, int CO_TOT)
{
    const int co0 = blockIdx.x * 16;
    const int b = blockIdx.y;
    const int tid = threadIdx.x;
    const int px = tid & 63;
    const int wg = tid >> 6;
    const int py = px / 7, pxx = px - py * 7;
    const bool act = px < 49;

    __shared__ float s_in[64][9][9];
    __shared__ float s_w[64][16][9];

    float acc[4] = {0.f, 0.f, 0.f, 0.f};

    for (int ci0 = 0; ci0 < CIN; ci0 += 64) {
        __syncthreads();
        for (int idx = tid; idx < 64 * 81; idx += 256) {
            int ci = idx / 81;
            int rem = idx - ci * 81;
            int r = rem / 9, c = rem - (rem / 9) * 9;
            float v = 0.f;
            if (r >= 1 && r <= 7 && c >= 1 && c <= 7)
                v = in[((size_t)(b * CIN + ci0 + ci) * 7 + (r - 1)) * 7 + (c - 1)];
            s_in[ci][r][c] = v;
        }
        for (int idx = tid; idx < 64 * 16 * 9; idx += 256) {
            int co = idx / 576;
            int rem = idx - co * 576;
            int ci = rem / 9, tap = rem - (rem / 9) * 9;
            s_w[ci][co][tap] = w[((size_t)(co0 + co) * CIN + ci0 + ci) * 9 + tap];
        }
        __syncthreads();
        if (act) {
            for (int ci = 0; ci < 64; ++ci) {
                #pragma unroll
                for (int ky = 0; ky < 3; ++ky)
                    #pragma unroll
                    for (int kx = 0; kx < 3; ++kx) {
                        float v = s_in[ci][py + ky][pxx + kx];
                        #pragma unroll
                        for (int j = 0; j < 4; ++j)
                            acc[j] = fmaf(v, s_w[ci][wg * 4 + j][ky * 3 + kx], acc[j]);
                    }
            }
        }
    }
    if (act) {
        const float kRS = 1.0f / sqrtf(1.0f + 1e-5f);
        #pragma unroll
        for (int j = 0; j < 4; ++j) {
            int cog = co0 + wg * 4 + j;
            float v = fmaxf(fmaf(acc[j], gam[cog] * kRS, bet[cog]), 0.f);
            out[(size_t)(b * CO_TOT + cog) * 49 + py * 7 + pxx] = v;
        }
    }
}

__global__ void pool3x3_kernel(const float* __restrict__ in, float* __restrict__ out)
{
    int o = blockIdx.x * 256 + threadIdx.x;
    if (o >= 16 * 128 * 9) return;
    int xo = o % 3;
    int yo = (o / 3) % 3;
    int bc = o / 9;
    const float* p = in + (size_t)bc * 49;
    float s = 0.f;
    #pragma unroll
    for (int ky = 0; ky < 3; ++ky)
        #pragma unroll
        for (int kx = 0; kx < 3; ++kx)
            s += p[(yo * 2 + ky) * 7 + xo * 2 + kx];
    out[o] = s * (1.0f / 9.0f);
}

__global__ __launch_bounds__(256)
void conv5_kernel(const float* __restrict__ in, const float* __restrict__ w,
                  const float* __restrict__ gam, const float* __restrict__ bet,
                  float* __restrict__ out)
{
    const int co0 = blockIdx.x * 16;
    const int b = blockIdx.y;
    const int tid = threadIdx.x;
    __shared__ float s_in[128][5][5];
    __shared__ float s_w[64][16][9];

    for (int idx = tid; idx < 128 * 25; idx += 256) {
        int ci = idx / 25;
        int rem = idx - ci * 25;
        int r = rem / 5, c = rem - (rem / 5) * 5;
        float v = 0.f;
        if (r >= 1 && r <= 3 && c >= 1 && c <= 3)
            v = in[((size_t)(b * 128 + ci) * 3 + (r - 1)) * 3 + (c - 1)];
        s_in[ci][r][c] = v;
    }

    float acc = 0.f;
    const int co = tid / 9;
    const int px = tid - co * 9;
    const int pyy = px / 3, pxx = px - pyy * 3;
    const bool act = tid < 144;

    for (int ci0 = 0; ci0 < 128; ci0 += 64) {
        __syncthreads();
        for (int idx = tid; idx < 64 * 16 * 9; idx += 256) {
            int c2 = idx / 576;
            int rem = idx - c2 * 576;
            int ci = rem / 9, tap = rem - (rem / 9) * 9;
            s_w[ci][c2][tap] = w[((size_t)(co0 + c2) * 128 + ci0 + ci) * 9 + tap];
        }
        __syncthreads();
        if (act) {
            for (int ci = 0; ci < 64; ++ci) {
                #pragma unroll
                for (int ky = 0; ky < 3; ++ky)
                    #pragma unroll
                    for (int kx = 0; kx < 3; ++kx)
                        acc = fmaf(s_in[ci0 + ci][pyy + ky][pxx + kx],
                                   s_w[ci][co][ky * 3 + kx], acc);
            }
        }
    }
    if (act) {
        const float kRS = 1.0f / sqrtf(1.0f + 1e-5f);
        int cog = co0 + co;
        out[(size_t)(b * 64 + cog) * 9 + px] =
            fmaxf(fmaf(acc, gam[cog] * kRS, bet[cog]), 0.f);
    }
}

__global__ void fc_kernel(const float* __restrict__ h5, const float* __restrict__ wfc,
                          float* __restrict__ feats)
{
    int o = blockIdx.x * 256 + threadIdx.x;
    if (o >= 16 * 128) return;
    int b = o >> 7, j = o & 127;
    const float* hp = h5 + b * 576;
    const float* wp = wfc + j * 576;
    float s = 0.f;
    for (int k = 0; k < 576; ++k) s = fmaf(hp[k], wp[k], s);
    feats[o] = s;
}

__global__ __launch_bounds__(256)
void attn_kernel(const float* __restrict__ feats, const float* __restrict__ mixw,
                 float* __restrict__ out)
{
    const int bo = blockIdx.x;
    const int b = bo >> 3, o = bo & 7;
    const int tid = threadIdx.x;
    __shared__ float s_att[4][3136];
    __shared__ float s_red[4];

    float mv[4];
    float mmax = -1e30f;
    #pragma unroll
    for (int g = 0; g < 4; ++g) { mv[g] = mixw[o * 4 + g]; mmax = fmaxf(mmax, mv[g]); }
    float msum = 0.f;
    #pragma unroll
    for (int g = 0; g < 4; ++g) { mv[g] = expf(mv[g] - mmax); msum += mv[g]; }
    #pragma unroll
    for (int g = 0; g < 4; ++g) mv[g] /= msum;

    const float LOG_R = 1.0986122886681098f;
    float winv[4];
    for (int g = 0; g < 4; ++g) {
        float f0 = feats[b * 128 + o * 16 + g * 4 + 0];
        float f1 = feats[b * 128 + o * 16 + g * 4 + 1];
        float f2 = feats[b * 128 + o * 16 + g * 4 + 2];
        float f3 = feats[b * 128 + o * 16 + g * 4 + 3];
        float m_x = 55.f / (1.f + expf(-f0));
        float m_y = 55.f / (1.f + expf(-f1));
        float r = expf((2.f / (1.f + expf(-f2)) - 1.f) * LOG_R);
        float rho = 1.6f / (1.f + expf(-f3)) - 0.8f;
        float denom = (-0.5f / (1.f - rho * rho)) * (1.f / 3136.f);
        float rin = 1.f / r;

        float ssum = 0.f;
        for (int p = tid; p < 3136; p += 256) {
            int i = p / 56;
            int j = p - i * 56;
            float dx = m_x - (float)i;
            float dy = m_y - (float)j;
            float quad = dx * dx * r + dy * dy * rin - 2.f * rho * dx * dy;
            float e = expf(denom * quad);
            s_att[g][p] = e;
            ssum += e;
        }
        #pragma unroll
        for (int off = 32; off > 0; off >>= 1) ssum += __shfl_down(ssum, off);
        if ((tid & 63) == 0) s_red[tid >> 6] = ssum;
        __syncthreads();
        winv[g] = mv[g] / (s_red[0] + s_red[1] + s_red[2] + s_red[3]);
        __syncthreads();
    }

    for (int p = tid; p < 3136; p += 256) {
        float v = 0.f;
        #pragma unroll
        for (int g = 0; g < 4; ++g) v += s_att[g][p] * winv[g];
        out[(size_t)bo * 3136 + p] = v;
    }
}

// ---------------------------------------------------------------------------

extern "C" void kernel_launch(void* const* d_in, const int* in_sizes, int n_in,
                              void* d_out, int out_size, void* d_ws, size_t ws_size,
                              hipStream_t stream)
{
    const float* x    = (const float*)d_in[0];
    const float* w1   = (const float*)d_in[1];
    const float* g1   = (const float*)d_in[2];
    const float* b1   = (const float*)d_in[3];
    const float* w2   = (const float*)d_in[4];
    const float* g2   = (const float*)d_in[5];
    const float* b2   = (const float*)d_in[6];
    const float* w3   = (const float*)d_in[7];
    const float* g3   = (const float*)d_in[8];
    const float* b3   = (const float*)d_in[9];
    const float* w4   = (const float*)d_in[10];
    const float* g4   = (const float*)d_in[11];
    const float* b4   = (const float*)d_in[12];
    const float* w5   = (const float*)d_in[13];
    const float* g5   = (const float*)d_in[14];
    const float* b5   = (const float*)d_in[15];
    const float* wfc  = (const float*)d_in[16];
    const float* mixw = (const float*)d_in[17];
    float* outp = (float*)d_out;

    // workspace layout (bytes)
    char* wsb = (char*)d_ws;
    unsigned short* wprep = (unsigned short*)wsb;            // reused conv1 then conv2
    wsb += 2621440 * sizeof(unsigned short);
    unsigned int* h1p = (unsigned int*)wsb;                  // 16*256*112*112 u32
    wsb += (size_t)51380224 * 4;
    float* p1 = (float*)wsb;  wsb += 200704 * 4;             // 16*256*7*7
    float* h3 = (float*)wsb;  wsb += 100352 * 4;
    float* h4 = (float*)wsb;  wsb += 100352 * 4;
    float* p2 = (float*)wsb;  wsb += 18432 * 4;
    float* h5 = (float*)wsb;  wsb += 9216 * 4;
    float* fts = (float*)wsb; wsb += 2048 * 4;

    // conv1: prep weights ([4][16][9][2][64][32] = 2,359,296 u16), MFMA conv
    prep_w_kernel<<<9216, 256, 0, stream>>>(w1, wprep, 512);
    conv_mfma_kernel<512, false><<<dim3(49, 4, 16), 256, 0, stream>>>(x, wprep, g1, b1, h1p);

    // conv2: re-prep weights ([4][8][9][2][64][32] = 1,179,648 u16)
    prep_w_kernel<<<4608, 256, 0, stream>>>(w2, wprep, 256);
    conv_mfma_kernel<256, true><<<dim3(49, 4, 16), 256, 0, stream>>>(h1p, wprep, g2, b2, p1);

    conv_small_kernel<256><<<dim3(8, 16), 256, 0, stream>>>(p1, w3, g3, b3, h3, 128);
    conv_small_kernel<128><<<dim3(8, 16), 256, 0, stream>>>(h3, w4, g4, b4, h4, 128);

    pool3x3_kernel<<<72, 256, 0, stream>>>(h4, p2);
    conv5_kernel<<<dim3(4, 16), 256, 0, stream>>>(p2, w5, g5, b5, h5);
    fc_kernel<<<8, 256, 0, stream>>>(h5, wfc, fts);
    attn_kernel<<<128, 256, 0, stream>>>(fts, mixw, outp);
}

// Round 4
// 1938.512 us; speedup vs baseline: 1.2541x; 1.2541x over previous
//
#include <hip/hip_runtime.h>
#include <math.h>

// ---------------------------------------------------------------------------
// BivariateNormalAttention pipeline.
// Round 3: conv1/conv2 MFMA implicit GEMM, rebalanced for measured pipes
//   (LDS ~256B/cyc/CU, L1 ~64B/cyc/CU):
//   - Wave tile M128xN64 (8x4 frags): 24 b128 LDS reads per 96 MFMA per tap.
//   - A AND B staged via global_load_lds (zero staging VALU / registers).
//     Inputs pre-split to hi/lo bf16 planes in gather layout with the XOR
//     quarter swizzle PRE-APPLIED in global memory (swizzle is tile-shift
//     invariant: ((18*gy+gx+19)>>1)&3).
//   - Block: 4 waves (2M x 2N), tile 256px x 128co, LDS 58KB -> 2 blocks/CU.
//   - B single-buffered per tap (16KB), staged with vmcnt(0)+barrier; A
//     single-buffered per ci32 chunk (43KB).
//   MFMA 16x16x32_bf16, 3-product hi/lo split (AhBh + AhBl + AlBh).
// ---------------------------------------------------------------------------

typedef __attribute__((ext_vector_type(8))) short short8v;
typedef __attribute__((ext_vector_type(4))) float f32x4;

__device__ __forceinline__ void split_bf16(float f, unsigned int& hi, unsigned int& lo)
{
    unsigned int u = __float_as_uint(f);
    hi = u >> 16;                                    // truncated bf16 hi
    float hif = __uint_as_float(u & 0xffff0000u);
    lo = __float_as_uint(f - hif) >> 16;             // residual, truncated
}

__device__ __forceinline__ void gld16(const void* g, void* l)
{
    __builtin_amdgcn_global_load_lds(
        (const __attribute__((address_space(1))) unsigned int*)g,
        (__attribute__((address_space(3))) unsigned int*)l, 16, 0, 0);
}

__global__ void zero_kernel(float* z) { z[threadIdx.x] = 0.f; }

// wp[y2][ch][tap][pl2][co128][k32] u16; within each co's 64B row the 16B
// quarters are pre-swizzled: phys quarter qp holds logical q = qp ^ ((co>>1)&3).
__global__ __launch_bounds__(256)
void prep_w_kernel(const float* __restrict__ w, unsigned short* __restrict__ wp, int CIN)
{
    int idx = blockIdx.x * 256 + threadIdx.x;
    int NCH = CIN >> 5;
    int total = 2 * NCH * 9 * 2 * 128 * 32;
    if (idx >= total) return;
    int kk = idx & 31;
    int co = (idx >> 5) & 127;
    int pl = (idx >> 12) & 1;
    int rest = idx >> 13;            // (y*NCH + ch)*9 + tap
    int tap = rest % 9;
    rest /= 9;
    int ch = rest % NCH;
    int y = rest / NCH;
    int qp = kk >> 3, e = kk & 7;
    int q = qp ^ ((co >> 1) & 3);
    int ci = ch * 32 + q * 8 + e;
    int cog = y * 128 + co;
    float f = w[((size_t)cog * CIN + ci) * 9 + tap];
    unsigned int hi, lo;
    split_bf16(f, hi, lo);
    wp[idx] = (unsigned short)(pl ? lo : hi);
}

// x[b][512][112][112] f32 -> xs[b][16ch][2pl][112][112][32ci] bf16,
// quarters pre-swizzled by pixel: qp = q ^ ((18*gy+gx+19)>>1 & 3)
__global__ __launch_bounds__(256)
void presplit_x_kernel(const float* __restrict__ x, unsigned short* __restrict__ xs)
{
    const int gy = blockIdx.x, ch = blockIdx.y, b = blockIdx.z;
    const int tid = threadIdx.x;
    __shared__ float s[32][113];
    for (int i = tid; i < 32 * 112; i += 256) {
        int ci = i / 112, xx = i - ci * 112;
        s[ci][xx] = x[(((size_t)(b * 16 + ch) * 32 + ci) * 112 + gy) * 112 + xx];
    }
    __syncthreads();
    unsigned int* oh = (unsigned int*)(xs + ((size_t)(b * 16 + ch) * 2 * 12544 + (size_t)gy * 112) * 32);
    unsigned int* ol = oh + 12544 * 16;   // plane stride in u32: 12544*32/2
    for (int i = tid; i < 112 * 16; i += 256) {
        int px = i >> 4, t = i & 15;          // t = u32 slot within 64B row
        int qp = t >> 2, ep = t & 3;
        int sw = ((18 * gy + px + 19) >> 1) & 3;
        int q = qp ^ sw;
        int ci0 = q * 8 + ep * 2;
        float f0 = s[ci0][px], f1 = s[ci0 + 1][px];
        unsigned int h0, l0, h1, l1;
        split_bf16(f0, h0, l0);
        split_bf16(f1, h1, l1);
        oh[(size_t)px * 16 + t] = h0 | (h1 << 16);
        ol[(size_t)px * 16 + t] = l0 | (l1 << 16);
    }
}

// POOL=false: conv1, input xs (pre-split x), writes h1s (pre-split layout).
// POOL=true : conv2, input h1s, writes pooled fp32 [B,256,7,7].
template<int CIN, bool POOL>
__global__ __launch_bounds__(256, 2)
void conv_mfma_kernel(const unsigned short* __restrict__ xs,
                      const unsigned short* __restrict__ wp,
                      const float* __restrict__ gam, const float* __restrict__ bet,
                      void* __restrict__ out_, const float* __restrict__ zerob)
{
    constexpr int NCH = CIN >> 5;
    __shared__ __align__(16) char sA[43008];   // [2pl][336px][64B]
    __shared__ __align__(16) char sB[16384];   // [2pl][128co][64B]

    const int tid = threadIdx.x;
    const int lane = tid & 63;
    const int wv = tid >> 6;
    const int wvm = wv >> 1, ng = wv & 1;
    const int m = lane & 15, kg = lane >> 4;
    const int ty = blockIdx.x / 7, tx = blockIdx.x % 7;
    const int yb = blockIdx.y;
    const int b = blockIdx.z;

    // ---- A staging geometry: 42 wave-issues of 1KB, round-robin over 4 waves
    int aoff[11];
    unsigned adst[11];
    #pragma unroll
    for (int k2 = 0; k2 < 11; ++k2) {
        int j = wv + 4 * k2;
        aoff[k2] = -1; adst[k2] = 0;
        if (j < 42) {
            int pl = j / 21, jj = j - pl * 21;
            int px = jj * 16 + (lane >> 2);
            int py = px / 18, pxx = px - py * 18;
            int gy = ty * 16 + py - 1, gx = tx * 16 + pxx - 1;
            bool valid = (px < 324) && ((unsigned)gy < 112u) && ((unsigned)gx < 112u);
            aoff[k2] = valid ? (pl * 802816 + ((gy * 112 + gx) << 6) + ((lane & 3) << 4)) : -1;
            adst[k2] = pl * 21504 + jj * 1024;
        }
    }
    const char* zb = (const char*)zerob + ((lane & 3) << 4);

    auto issueA = [&](int ch) {
        const char* xbase = (const char*)xs + (size_t)(b * NCH + ch) * 1605632;
        #pragma unroll
        for (int k2 = 0; k2 < 11; ++k2) {
            if (wv + 4 * k2 < 42) {
                const char* g = (aoff[k2] >= 0) ? (xbase + aoff[k2]) : zb;
                gld16(g, sA + adst[k2]);
            }
        }
    };
    const char* wbase = (const char*)wp + (size_t)yb * ((size_t)NCH * 9 * 16384);
    auto issueB = [&](int flat) {
        const char* gb = wbase + (size_t)flat * 16384 + (wv << 12) + (lane << 4);
        #pragma unroll
        for (int j2 = 0; j2 < 4; ++j2)
            gld16(gb + j2 * 1024, sB + (wv << 12) + j2 * 1024);
    };

    f32x4 acc[8][4];
    #pragma unroll
    for (int i = 0; i < 8; ++i)
        #pragma unroll
        for (int j = 0; j < 4; ++j)
            acc[i][j] = (f32x4){0.f, 0.f, 0.f, 0.f};

    issueA(0);
    issueB(0);
    asm volatile("s_waitcnt vmcnt(0)" ::: "memory");
    __syncthreads();

    for (int ch = 0; ch < NCH; ++ch) {
        #pragma unroll
        for (int tap = 0; tap < 9; ++tap) {
            const int ky = tap / 3, kx = tap % 3;
            // B frags (LDS, pre-swizzled by co)
            short8v Bf[8];
            #pragma unroll
            for (int nf = 0; nf < 4; ++nf) {
                int col = ng * 64 + nf * 16 + m;
                int off = col * 64 + ((kg ^ ((col >> 1) & 3)) << 4);
                Bf[nf * 2 + 0] = *(const short8v*)(sB + off);
                Bf[nf * 2 + 1] = *(const short8v*)(sB + 8192 + off);
            }
            #pragma unroll
            for (int mf = 0; mf < 8; ++mf) {
                int ap = (wvm * 8 + mf + ky) * 18 + kx + m;
                int off = ap * 64 + ((kg ^ ((ap >> 1) & 3)) << 4);
                short8v Ah = *(const short8v*)(sA + off);
                short8v Al = *(const short8v*)(sA + 21504 + off);
                #pragma unroll
                for (int nf = 0; nf < 4; ++nf) {
                    acc[mf][nf] = __builtin_amdgcn_mfma_f32_16x16x32_bf16(Ah, Bf[nf * 2 + 0], acc[mf][nf], 0, 0, 0);
                    acc[mf][nf] = __builtin_amdgcn_mfma_f32_16x16x32_bf16(Ah, Bf[nf * 2 + 1], acc[mf][nf], 0, 0, 0);
                    acc[mf][nf] = __builtin_amdgcn_mfma_f32_16x16x32_bf16(Al, Bf[nf * 2 + 0], acc[mf][nf], 0, 0, 0);
                }
            }
            __syncthreads();                     // done reading sB (and sA at tap 8)
            int flat = ch * 9 + tap + 1;
            if (flat < NCH * 9) issueB(flat);
            if (tap == 8 && ch + 1 < NCH) issueA(ch + 1);
            asm volatile("s_waitcnt vmcnt(0)" ::: "memory");
            __syncthreads();                     // staged data visible to all waves
        }
    }

    const float kRS = 1.0f / sqrtf(1.0f + 1e-5f);

    if (!POOL) {
        // write h1s[b][ch2 8][pl2][gy][gx][32] bf16, pixel-swizzled quarters
        unsigned short* h1s = (unsigned short*)out_;
        #pragma unroll
        for (int mf = 0; mf < 8; ++mf) {
            int gy = ty * 16 + wvm * 8 + mf;
            #pragma unroll
            for (int nf = 0; nf < 4; ++nf) {
                int co = yb * 128 + ng * 64 + nf * 16 + m;
                float sc = gam[co] * kRS, bi = bet[co];
                int ch2 = co >> 5, sl = co & 31, q = sl >> 3, e = sl & 7;
                size_t base = (size_t)(b * 8 + ch2) * 802816;   // u16 per (b,ch2)
                #pragma unroll
                for (int r = 0; r < 4; ++r) {
                    int gx = tx * 16 + kg * 4 + r;
                    float v = fmaxf(fmaf(acc[mf][nf][r], sc, bi), 0.f);
                    unsigned int hi, lo;
                    split_bf16(v, hi, lo);
                    int sw = ((18 * gy + gx + 19) >> 1) & 3;
                    size_t po = base + ((size_t)gy * 112 + gx) * 32 + (size_t)((q ^ sw) * 8 + e);
                    h1s[po] = (unsigned short)hi;
                    h1s[po + 401408] = (unsigned short)lo;
                }
            }
        }
    } else {
        // fused BN+ReLU + 16x16 avg pool (tile == pool window)
        __syncthreads();
        float* spool = (float*)sB;
        #pragma unroll
        for (int nf = 0; nf < 4; ++nf) {
            int co = yb * 128 + ng * 64 + nf * 16 + m;
            float sc = gam[co] * kRS, bi = bet[co];
            float s = 0.f;
            #pragma unroll
            for (int mf = 0; mf < 8; ++mf)
                #pragma unroll
                for (int r = 0; r < 4; ++r)
                    s += fmaxf(fmaf(acc[mf][nf][r], sc, bi), 0.f);
            s += __shfl_xor(s, 16);
            s += __shfl_xor(s, 32);
            if (lane < 16) spool[wv * 64 + nf * 16 + m] = s;
        }
        __syncthreads();
        if (tid < 128) {
            int ngx = tid >> 6, cl = tid & 63;
            float s = spool[ngx * 64 + cl] + spool[(2 + ngx) * 64 + cl];
            float* p1o = (float*)out_;
            p1o[(((size_t)b * 256 + yb * 128 + ngx * 64 + cl) * 7 + ty) * 7 + tx] = s * (1.f / 256.f);
        }
    }
}

// ---------------- small downstream stages (unchanged) ----------------------

template<int CIN>
__global__ __launch_bounds__(256)
void conv_small_kernel(const float* __restrict__ in, const float* __restrict__ w,
                       const float* __restrict__ gam, const float* __restrict__ bet,
                       float* __restrict__ out, int CO_TOT)
{
    const int co0 = blockIdx.x * 16;
    const int b = blockIdx.y;
    const int tid = threadIdx.x;
    const int px = tid & 63;
    const int wg = tid >> 6;
    const int py = px / 7, pxx = px - py * 7;
    const bool act = px < 49;

    __shared__ float s_in[64][9][9];
    __shared__ float s_w[64][16][9];

    float acc[4] = {0.f, 0.f, 0.f, 0.f};

    for (int ci0 = 0; ci0 < CIN; ci0 += 64) {
        __syncthreads();
        for (int idx = tid; idx < 64 * 81; idx += 256) {
            int ci = idx / 81;
            int rem = idx - ci * 81;
            int r = rem / 9, c = rem - (rem / 9) * 9;
            float v = 0.f;
            if (r >= 1 && r <= 7 && c >= 1 && c <= 7)
                v = in[((size_t)(b * CIN + ci0 + ci) * 7 + (r - 1)) * 7 + (c - 1)];
            s_in[ci][r][c] = v;
        }
        for (int idx = tid; idx < 64 * 16 * 9; idx += 256) {
            int co = idx / 576;
            int rem = idx - co * 576;
            int ci = rem / 9, tap = rem - (rem / 9) * 9;
            s_w[ci][co][tap] = w[((size_t)(co0 + co) * CIN + ci0 + ci) * 9 + tap];
        }
        __syncthreads();
        if (act) {
            for (int ci = 0; ci < 64; ++ci) {
                #pragma unroll
                for (int ky = 0; ky < 3; ++ky)
                    #pragma unroll
                    for (int kx = 0; kx < 3; ++kx) {
                        float v = s_in[ci][py + ky][pxx + kx];
                        #pragma unroll
                        for (int j = 0; j < 4; ++j)
                            acc[j] = fmaf(v, s_w[ci][wg * 4 + j][ky * 3 + kx], acc[j]);
                    }
            }
        }
    }
    if (act) {
        const float kRS = 1.0f / sqrtf(1.0f + 1e-5f);
        #pragma unroll
        for (int j = 0; j < 4; ++j) {
            int cog = co0 + wg * 4 + j;
            float v = fmaxf(fmaf(acc[j], gam[cog] * kRS, bet[cog]), 0.f);
            out[(size_t)(b * CO_TOT + cog) * 49 + py * 7 + pxx] = v;
        }
    }
}

__global__ void pool3x3_kernel(const float* __restrict__ in, float* __restrict__ out)
{
    int o = blockIdx.x * 256 + threadIdx.x;
    if (o >= 16 * 128 * 9) return;
    int xo = o % 3;
    int yo = (o / 3) % 3;
    int bc = o / 9;
    const float* p = in + (size_t)bc * 49;
    float s = 0.f;
    #pragma unroll
    for (int ky = 0; ky < 3; ++ky)
        #pragma unroll
        for (int kx = 0; kx < 3; ++kx)
            s += p[(yo * 2 + ky) * 7 + xo * 2 + kx];
    out[o] = s * (1.0f / 9.0f);
}

__global__ __launch_bounds__(256)
void conv5_kernel(const float* __restrict__ in, const float* __restrict__ w,
                  const float* __restrict__ gam, const float* __restrict__ bet,
                  float* __restrict__ out)
{
    const int co0 = blockIdx.x * 16;
    const int b = blockIdx.y;
    const int tid = threadIdx.x;
    __shared__ float s_in[128][5][5];
    __shared__ float s_w[64][16][9];

    for (int idx = tid; idx < 128 * 25; idx += 256) {
        int ci = idx / 25;
        int rem = idx - ci * 25;
        int r = rem / 5, c = rem - (rem / 5) * 5;
        float v = 0.f;
        if (r >= 1 && r <= 3 && c >= 1 && c <= 3)
            v = in[((size_t)(b * 128 + ci) * 3 + (r - 1)) * 3 + (c - 1)];
        s_in[ci][r][c] = v;
    }

    float acc = 0.f;
    const int co = tid / 9;
    const int px = tid - co * 9;
    const int pyy = px / 3, pxx = px - pyy * 3;
    const bool act = tid < 144;

    for (int ci0 = 0; ci0 < 128; ci0 += 64) {
        __syncthreads();
        for (int idx = tid; idx < 64 * 16 * 9; idx += 256) {
            int c2 = idx / 576;
            int rem = idx - c2 * 576;
            int ci = rem / 9, tap = rem - (rem / 9) * 9;
            s_w[ci][c2][tap] = w[((size_t)(co0 + c2) * 128 + ci0 + ci) * 9 + tap];
        }
        __syncthreads();
        if (act) {
            for (int ci = 0; ci < 64; ++ci) {
                #pragma unroll
                for (int ky = 0; ky < 3; ++ky)
                    #pragma unroll
                    for (int kx = 0; kx < 3; ++kx)
                        acc = fmaf(s_in[ci0 + ci][pyy + ky][pxx + kx],
                                   s_w[ci][co][ky * 3 + kx], acc);
            }
        }
    }
    if (act) {
        const float kRS = 1.0f / sqrtf(1.0f + 1e-5f);
        int cog = co0 + co;
        out[(size_t)(b * 64 + cog) * 9 + px] =
            fmaxf(fmaf(acc, gam[cog] * kRS, bet[cog]), 0.f);
    }
}

__global__ void fc_kernel(const float* __restrict__ h5, const float* __restrict__ wfc,
                          float* __restrict__ feats)
{
    int o = blockIdx.x * 256 + threadIdx.x;
    if (o >= 16 * 128) return;
    int b = o >> 7, j = o & 127;
    const float* hp = h5 + b * 576;
    const float* wp = wfc + j * 576;
    float s = 0.f;
    for (int k = 0; k < 576; ++k) s = fmaf(hp[k], wp[k], s);
    feats[o] = s;
}

__global__ __launch_bounds__(256)
void attn_kernel(const float* __restrict__ feats, const float* __restrict__ mixw,
                 float* __restrict__ out)
{
    const int bo = blockIdx.x;
    const int b = bo >> 3, o = bo & 7;
    const int tid = threadIdx.x;
    __shared__ float s_att[4][3136];
    __shared__ float s_red[4];

    float mv[4];
    float mmax = -1e30f;
    #pragma unroll
    for (int g = 0; g < 4; ++g) { mv[g] = mixw[o * 4 + g]; mmax = fmaxf(mmax, mv[g]); }
    float msum = 0.f;
    #pragma unroll
    for (int g = 0; g < 4; ++g) { mv[g] = expf(mv[g] - mmax); msum += mv[g]; }
    #pragma unroll
    for (int g = 0; g < 4; ++g) mv[g] /= msum;

    const float LOG_R = 1.0986122886681098f;
    float winv[4];
    for (int g = 0; g < 4; ++g) {
        float f0 = feats[b * 128 + o * 16 + g * 4 + 0];
        float f1 = feats[b * 128 + o * 16 + g * 4 + 1];
        float f2 = feats[b * 128 + o * 16 + g * 4 + 2];
        float f3 = feats[b * 128 + o * 16 + g * 4 + 3];
        float m_x = 55.f / (1.f + expf(-f0));
        float m_y = 55.f / (1.f + expf(-f1));
        float r = expf((2.f / (1.f + expf(-f2)) - 1.f) * LOG_R);
        float rho = 1.6f / (1.f + expf(-f3)) - 0.8f;
        float denom = (-0.5f / (1.f - rho * rho)) * (1.f / 3136.f);
        float rin = 1.f / r;

        float ssum = 0.f;
        for (int p = tid; p < 3136; p += 256) {
            int i = p / 56;
            int j = p - i * 56;
            float dx = m_x - (float)i;
            float dy = m_y - (float)j;
            float quad = dx * dx * r + dy * dy * rin - 2.f * rho * dx * dy;
            float e = expf(denom * quad);
            s_att[g][p] = e;
            ssum += e;
        }
        #pragma unroll
        for (int off = 32; off > 0; off >>= 1) ssum += __shfl_down(ssum, off);
        if ((tid & 63) == 0) s_red[tid >> 6] = ssum;
        __syncthreads();
        winv[g] = mv[g] / (s_red[0] + s_red[1] + s_red[2] + s_red[3]);
        __syncthreads();
    }

    for (int p = tid; p < 3136; p += 256) {
        float v = 0.f;
        #pragma unroll
        for (int g = 0; g < 4; ++g) v += s_att[g][p] * winv[g];
        out[(size_t)bo * 3136 + p] = v;
    }
}

// ---------------------------------------------------------------------------

extern "C" void kernel_launch(void* const* d_in, const int* in_sizes, int n_in,
                              void* d_out, int out_size, void* d_ws, size_t ws_size,
                              hipStream_t stream)
{
    const float* x    = (const float*)d_in[0];
    const float* w1   = (const float*)d_in[1];
    const float* g1   = (const float*)d_in[2];
    const float* b1   = (const float*)d_in[3];
    const float* w2   = (const float*)d_in[4];
    const float* g2   = (const float*)d_in[5];
    const float* b2   = (const float*)d_in[6];
    const float* w3   = (const float*)d_in[7];
    const float* g3   = (const float*)d_in[8];
    const float* b3   = (const float*)d_in[9];
    const float* w4   = (const float*)d_in[10];
    const float* g4   = (const float*)d_in[11];
    const float* b4   = (const float*)d_in[12];
    const float* w5   = (const float*)d_in[13];
    const float* g5   = (const float*)d_in[14];
    const float* b5   = (const float*)d_in[15];
    const float* wfc  = (const float*)d_in[16];
    const float* mixw = (const float*)d_in[17];
    float* outp = (float*)d_out;

    // workspace layout (bytes), total ~622 MB
    char* wsb = (char*)d_ws;
    unsigned short* wp = (unsigned short*)wsb;   wsb += (size_t)2359296 * 2;      // 4.7MB (reused)
    unsigned short* xs = (unsigned short*)wsb;   wsb += (size_t)16*16*2*12544*32*2;  // 411MB
    unsigned short* h1s = (unsigned short*)wsb;  wsb += (size_t)16*8*2*12544*32*2;   // 205.5MB
    float* p1 = (float*)wsb;  wsb += 200704 * 4;
    float* h3 = (float*)wsb;  wsb += 100352 * 4;
    float* h4 = (float*)wsb;  wsb += 100352 * 4;
    float* p2 = (float*)wsb;  wsb += 18432 * 4;
    float* h5 = (float*)wsb;  wsb += 9216 * 4;
    float* fts = (float*)wsb; wsb += 2048 * 4;
    float* zerob = (float*)wsb; wsb += 64 * 4;

    zero_kernel<<<1, 64, 0, stream>>>(zerob);
    presplit_x_kernel<<<dim3(112, 16, 16), 256, 0, stream>>>(x, xs);

    prep_w_kernel<<<9216, 256, 0, stream>>>(w1, wp, 512);
    conv_mfma_kernel<512, false><<<dim3(49, 2, 16), 256, 0, stream>>>(xs, wp, g1, b1, h1s, zerob);

    prep_w_kernel<<<4608, 256, 0, stream>>>(w2, wp, 256);
    conv_mfma_kernel<256, true><<<dim3(49, 2, 16), 256, 0, stream>>>(h1s, wp, g2, b2, p1, zerob);

    conv_small_kernel<256><<<dim3(8, 16), 256, 0, stream>>>(p1, w3, g3, b3, h3, 128);
    conv_small_kernel<128><<<dim3(8, 16), 256, 0, stream>>>(h3, w4, g4, b4, h4, 128);

    pool3x3_kernel<<<72, 256, 0, stream>>>(h4, p2);
    conv5_kernel<<<dim3(4, 16), 256, 0, stream>>>(p2, w5, g5, b5, h5);
    fc_kernel<<<8, 256, 0, stream>>>(h5, wfc, fts);
    attn_kernel<<<128, 256, 0, stream>>>(fts, mixw, outp);
}